// Round 10
// baseline (69.068 us; speedup 1.0000x reference)
//
#include <hip/hip_runtime.h>
#include <math.h>
#include <stdint.h>

#define D_MODEL 512
#define D_STATE 16
#define NSEQ    2048
#define NBATCH  4
#define EPSF    1e-8f
#define LN_EPSF 1e-5f
#define DT      (1.0f / 2048.0f)

typedef __attribute__((ext_vector_type(8))) short short8;
typedef __attribute__((ext_vector_type(4))) float floatx4;

__device__ __forceinline__ ushort f2bf(float f) {
    uint32_t u = __float_as_uint(f);
    return (ushort)((u + 0x7fffu + ((u >> 16) & 1u)) >> 16);
}

// ---------------------------------------------------------------------------
// kP (512 blocks x 256): per block = 16 rows (= one scan chunk).
//  - W_gate f32->bf16 slice (64 thr)
//  - Bu dot over LDS-staged W_B*B_bar
//  - 16-row LOCAL scan -> hL[row][s], chunk end -> states[chunk][s]
// ---------------------------------------------------------------------------
__global__ __launch_bounds__(256) void kP(const float* __restrict__ x,
                                          const float* __restrict__ A_log,
                                          const float* __restrict__ W_B,
                                          const float* __restrict__ Wg,
                                          ushort* __restrict__ wgb,
                                          float* __restrict__ hL,
                                          float* __restrict__ states) {
    __shared__ float wb[D_STATE][D_MODEL + 4];
    __shared__ float bbars[16], abars[16];
    __shared__ float w4[4][16];
    const int tid = threadIdx.x, lane = tid & 63, wave = tid >> 6;

    if (tid < 64) {                       // W_gate cvt slice
        int i = blockIdx.x * 64 + tid;
        const float4* sp = (const float4*)Wg + (size_t)i * 2;
        float4 a = sp[0], b = sp[1];
        float v[8] = {a.x, a.y, a.z, a.w, b.x, b.y, b.z, b.w};
        short8 o;
        #pragma unroll
        for (int j = 0; j < 8; ++j) o[j] = (short)f2bf(v[j]);
        *(short8*)(wgb + (size_t)i * 8) = o;
    }
    if (tid < 16) {
        float A    = -fminf(fmaxf(expf(A_log[tid]), EPSF), 10.0f);
        float Abar = expf(A * DT);
        abars[tid] = Abar;
        bbars[tid] = (fabsf(A) > EPSF) ? (Abar - 1.0f) / (A + EPSF) : DT;
    }
    __syncthreads();
    for (int i = tid; i < D_STATE * D_MODEL; i += 256) {
        int s = i >> 9, m = i & 511;
        wb[s][m] = W_B[i] * bbars[s];
    }
    __syncthreads();

    const int s    = lane & 15;
    const int q    = lane >> 4;
    const int rloc = q + (wave << 2);
    const int row  = blockIdx.x * 16 + rloc;
    const float* xr = x + (size_t)row * D_MODEL;

    float acc = 0.f;
    #pragma unroll 4
    for (int m = 0; m < D_MODEL; m += 4) {
        float4 xv = *(const float4*)(xr + m);
        float4 wv = *(const float4*)(&wb[s][m]);
        acc += xv.x * wv.x + xv.y * wv.y + xv.z * wv.z + xv.w * wv.w;
    }

    float abar = abars[s];
    float a = abar, b = acc;
    {
        float ap = __shfl_up(a, 16), bp = __shfl_up(b, 16);
        if (lane >= 16) { b = a * bp + b; a = a * ap; }
    }
    {
        float ap = __shfl_up(a, 32), bp = __shfl_up(b, 32);
        if (lane >= 32) { b = a * bp + b; a = a * ap; }
    }
    if (q == 3) w4[wave][s] = b;
    __syncthreads();
    float a4 = abar * abar; a4 = a4 * a4;
    float pb = 0.f;
    for (int w = 0; w < wave; ++w) pb = a4 * pb + w4[w][s];
    float hloc = a * pb + b;

    hL[(size_t)row * D_STATE + s] = hloc;
    if (rloc == 15) states[(size_t)blockIdx.x * D_STATE + s] = hloc;
}

// ---------------------------------------------------------------------------
// kc (512 blocks x 256): h finalize + BARRIER-FREE register-streaming gate
// GEMM (B-frags direct global->VGPR, 1-deep prefetch, no LDS staging)
// + f32 h@W_C^T + blend + LayerNorm.
// ---------------------------------------------------------------------------
#define CBM 16
__global__ __launch_bounds__(256, 2) void kc_fused(
    const float*  __restrict__ x,      // (8192,512)
    const ushort* __restrict__ Wg,     // bf16 (512,512)
    const float*  __restrict__ hL,     // (8192,16)
    const float*  __restrict__ states, // (512,16)
    const float*  __restrict__ A_log,
    const float*  __restrict__ W_C,    // (512,16)
    const float*  __restrict__ Dvec,
    const float*  __restrict__ bg,
    const float*  __restrict__ gamma,
    const float*  __restrict__ beta,
    float* __restrict__ out) {
    __shared__ float stgbuf[2048];          // 8 KB (chunk states)
    __shared__ float hsf[CBM][D_STATE];     // 1 KB
    __shared__ float red[4][CBM][2];        // 512 B

    const int tid  = threadIdx.x;
    const int lane = tid & 63, wave = tid >> 6;
    const int r0   = blockIdx.x * CBM;
    const int fr   = lane & 15, kg = lane >> 4;
    const int colw = wave * 128;

    // ---- chunk-prefix combine -> hsf (f32) ----
    const int c0 = blockIdx.x & 127;
    for (int i = tid; i < c0 * 16; i += 256)
        stgbuf[i] = states[(size_t)(blockIdx.x - c0) * 16 + i];
    __syncthreads();
    {
        int s = tid & 15, nloc = tid >> 4;
        float A   = -fminf(fmaxf(expf(A_log[s]), EPSF), 10.0f);
        float a16 = expf(A * DT * 16.0f);
        float p = 0.f;
        for (int cc = 0; cc < c0; ++cc) p = a16 * p + stgbuf[cc * 16 + s];
        float hv = expf(A * DT * (float)(nloc + 1)) * p
                 + hL[(size_t)(r0 + nloc) * D_STATE + s];
        hsf[nloc][s] = fminf(fmaxf(hv, -10.f), 10.f);
    }
    // (hsf consumed after the GEMM; the pre-epilogue __syncthreads covers it)

    // ---- barrier-free register-streaming GEMM ----
    // A: lane loads x[r0+fr][kc + kg*8 .. +8] (f32 -> bf16 in reg)
    // B: lane loads Wg[colw + j*16 + fr][kc + kg*8 .. +8] (short8), j=0..7
    const float*  aBase = x  + (size_t)(r0  + fr) * D_MODEL + kg * 8;
    const ushort* bBase = Wg + (size_t)(colw + fr) * D_MODEL + kg * 8;

    float4 a0 = *(const float4*)(aBase);
    float4 a1 = *(const float4*)(aBase + 4);
    short8 bc0 = *(const short8*)(bBase);
    short8 bc1 = *(const short8*)(bBase + (size_t)1 * 16 * D_MODEL);
    short8 bc2 = *(const short8*)(bBase + (size_t)2 * 16 * D_MODEL);
    short8 bc3 = *(const short8*)(bBase + (size_t)3 * 16 * D_MODEL);
    short8 bc4 = *(const short8*)(bBase + (size_t)4 * 16 * D_MODEL);
    short8 bc5 = *(const short8*)(bBase + (size_t)5 * 16 * D_MODEL);
    short8 bc6 = *(const short8*)(bBase + (size_t)6 * 16 * D_MODEL);
    short8 bc7 = *(const short8*)(bBase + (size_t)7 * 16 * D_MODEL);

    floatx4 acc[8] = {};
    #pragma unroll
    for (int t = 0; t < 16; ++t) {
        const int kn = (t + 1) * 32;         // next K-slice offset
        float4 n0, n1;
        short8 bn0, bn1, bn2, bn3, bn4, bn5, bn6, bn7;
        if (t < 15) {                        // issue next-iter loads FIRST
            n0  = *(const float4*)(aBase + kn);
            n1  = *(const float4*)(aBase + kn + 4);
            bn0 = *(const short8*)(bBase + kn);
            bn1 = *(const short8*)(bBase + (size_t)1 * 16 * D_MODEL + kn);
            bn2 = *(const short8*)(bBase + (size_t)2 * 16 * D_MODEL + kn);
            bn3 = *(const short8*)(bBase + (size_t)3 * 16 * D_MODEL + kn);
            bn4 = *(const short8*)(bBase + (size_t)4 * 16 * D_MODEL + kn);
            bn5 = *(const short8*)(bBase + (size_t)5 * 16 * D_MODEL + kn);
            bn6 = *(const short8*)(bBase + (size_t)6 * 16 * D_MODEL + kn);
            bn7 = *(const short8*)(bBase + (size_t)7 * 16 * D_MODEL + kn);
        }
        short8 af;
        {
            float v[8] = {a0.x,a0.y,a0.z,a0.w,a1.x,a1.y,a1.z,a1.w};
            #pragma unroll
            for (int e = 0; e < 8; ++e) af[e] = (short)f2bf(v[e]);
        }
        acc[0] = __builtin_amdgcn_mfma_f32_16x16x32_bf16(af, bc0, acc[0], 0, 0, 0);
        acc[1] = __builtin_amdgcn_mfma_f32_16x16x32_bf16(af, bc1, acc[1], 0, 0, 0);
        acc[2] = __builtin_amdgcn_mfma_f32_16x16x32_bf16(af, bc2, acc[2], 0, 0, 0);
        acc[3] = __builtin_amdgcn_mfma_f32_16x16x32_bf16(af, bc3, acc[3], 0, 0, 0);
        acc[4] = __builtin_amdgcn_mfma_f32_16x16x32_bf16(af, bc4, acc[4], 0, 0, 0);
        acc[5] = __builtin_amdgcn_mfma_f32_16x16x32_bf16(af, bc5, acc[5], 0, 0, 0);
        acc[6] = __builtin_amdgcn_mfma_f32_16x16x32_bf16(af, bc6, acc[6], 0, 0, 0);
        acc[7] = __builtin_amdgcn_mfma_f32_16x16x32_bf16(af, bc7, acc[7], 0, 0, 0);
        if (t < 15) {
            a0 = n0; a1 = n1;
            bc0 = bn0; bc1 = bn1; bc2 = bn2; bc3 = bn3;
            bc4 = bn4; bc5 = bn5; bc6 = bn6; bc7 = bn7;
        }
    }

    __syncthreads();    // hsf visible to all waves (written pre-GEMM)

    // ---- epilogue: y = h@W_C^T (f32 VALU) + D*x, blend, LayerNorm ----
    float vsum[4] = {}, vsq[4] = {};
    #pragma unroll
    for (int j = 0; j < 8; ++j) {
        int col = colw + j * 16 + fr;
        float dv = Dvec[col], bgv = bg[col];
        const float4* wcp = (const float4*)(W_C + (size_t)col * D_STATE);
        float4 w0 = wcp[0], w1 = wcp[1], w2 = wcp[2], w3 = wcp[3];
        #pragma unroll
        for (int q = 0; q < 4; ++q) {
            int rl = kg * 4 + q;
            float xv = x[(size_t)(r0 + rl) * D_MODEL + col];
            const float* hp = hsf[rl];
            float yv = dv * xv
                + hp[0]*w0.x + hp[1]*w0.y + hp[2]*w0.z + hp[3]*w0.w
                + hp[4]*w1.x + hp[5]*w1.y + hp[6]*w1.z + hp[7]*w1.w
                + hp[8]*w2.x + hp[9]*w2.y + hp[10]*w2.z + hp[11]*w2.w
                + hp[12]*w3.x + hp[13]*w3.y + hp[14]*w3.z + hp[15]*w3.w;
            float lg = acc[j][q] + bgv;
            float gt = 1.f / (1.f + expf(-lg));
            float v  = gt * yv + (1.f - gt) * xv;
            acc[j][q] = v;
            vsum[q] += v;
            vsq[q]  += v * v;
        }
    }
    #pragma unroll
    for (int off = 1; off < 16; off <<= 1) {
        #pragma unroll
        for (int q = 0; q < 4; ++q) {
            vsum[q] += __shfl_xor(vsum[q], off);
            vsq[q]  += __shfl_xor(vsq[q], off);
        }
    }
    if (fr == 0) {
        #pragma unroll
        for (int q = 0; q < 4; ++q) {
            red[wave][kg * 4 + q][0] = vsum[q];
            red[wave][kg * 4 + q][1] = vsq[q];
        }
    }
    __syncthreads();
    float mu[4], rs[4];
    #pragma unroll
    for (int q = 0; q < 4; ++q) {
        int rl = kg * 4 + q;
        float s = 0.f, ss = 0.f;
        #pragma unroll
        for (int w = 0; w < 4; ++w) { s += red[w][rl][0]; ss += red[w][rl][1]; }
        float m   = s * (1.f / (float)D_MODEL);
        float var = ss * (1.f / (float)D_MODEL) - m * m;
        mu[q] = m;
        rs[q] = rsqrtf(var + LN_EPSF);
    }
    #pragma unroll
    for (int j = 0; j < 8; ++j) {
        int col = colw + j * 16 + fr;
        float ga = gamma[col], be = beta[col];
        #pragma unroll
        for (int q = 0; q < 4; ++q)
            out[(size_t)(r0 + kg * 4 + q) * D_MODEL + col] =
                (acc[j][q] - mu[q]) * rs[q] * ga + be;
    }
}

// ---------------------------------------------------------------------------
extern "C" void kernel_launch(void* const* d_in, const int* in_sizes, int n_in,
                              void* d_out, int out_size, void* d_ws, size_t ws_size,
                              hipStream_t stream) {
    const float* x     = (const float*)d_in[0];
    const float* A_log = (const float*)d_in[1];
    const float* W_B   = (const float*)d_in[2];
    const float* W_C   = (const float*)d_in[3];
    const float* Dv    = (const float*)d_in[4];
    const float* Wg    = (const float*)d_in[5];
    const float* bg    = (const float*)d_in[6];
    const float* gamma = (const float*)d_in[7];
    const float* beta  = (const float*)d_in[8];
    float* out = (float*)d_out;

    const int rows = NBATCH * NSEQ;                            // 8192

    ushort* wgb    = (ushort*)d_ws;                            // 512 KB
    float*  hL     = (float*)(wgb + (size_t)D_MODEL * D_MODEL);// 512 KB
    float*  states = hL + (size_t)rows * D_STATE;              // 32 KB

    hipLaunchKernelGGL(kP, dim3(rows / 16), dim3(256), 0, stream,
                       x, A_log, W_B, Wg, wgb, hL, states);
    hipLaunchKernelGGL(kc_fused, dim3(rows / CBM), dim3(256), 0, stream,
                       x, wgb, hL, states, A_log, W_C, Dv, bg, gamma, beta, out);
}

// Round 12
// 58.551 us; speedup vs baseline: 1.1796x; 1.1796x over previous
//
#include <hip/hip_runtime.h>
#include <math.h>
#include <stdint.h>

#define D_MODEL 512
#define D_STATE 16
#define NSEQ    2048
#define NBATCH  4
#define EPSF    1e-8f
#define LN_EPSF 1e-5f
#define DT      (1.0f / 2048.0f)

typedef __attribute__((ext_vector_type(8))) short short8;
typedef __attribute__((ext_vector_type(4))) float floatx4;

__device__ __forceinline__ ushort f2bf(float f) {
    uint32_t u = __float_as_uint(f);
    return (ushort)((u + 0x7fffu + ((u >> 16) & 1u)) >> 16);
}

// ---------------------------------------------------------------------------
// kP (512 blocks x 256): per block = 16 rows (= one scan chunk).
// Byte-identical to the validated R7 version.
// ---------------------------------------------------------------------------
__global__ __launch_bounds__(256) void kP(const float* __restrict__ x,
                                          const float* __restrict__ A_log,
                                          const float* __restrict__ W_B,
                                          const float* __restrict__ Wg,
                                          ushort* __restrict__ wgb,
                                          float* __restrict__ hL,
                                          float* __restrict__ states) {
    __shared__ float wb[D_STATE][D_MODEL + 4];
    __shared__ float bbars[16], abars[16];
    __shared__ float w4[4][16];
    const int tid = threadIdx.x, lane = tid & 63, wave = tid >> 6;

    if (tid < 64) {                       // W_gate cvt slice
        int i = blockIdx.x * 64 + tid;
        const float4* sp = (const float4*)Wg + (size_t)i * 2;
        float4 a = sp[0], b = sp[1];
        float v[8] = {a.x, a.y, a.z, a.w, b.x, b.y, b.z, b.w};
        short8 o;
        #pragma unroll
        for (int j = 0; j < 8; ++j) o[j] = (short)f2bf(v[j]);
        *(short8*)(wgb + (size_t)i * 8) = o;
    }
    if (tid < 16) {
        float A    = -fminf(fmaxf(expf(A_log[tid]), EPSF), 10.0f);
        float Abar = expf(A * DT);
        abars[tid] = Abar;
        bbars[tid] = (fabsf(A) > EPSF) ? (Abar - 1.0f) / (A + EPSF) : DT;
    }
    __syncthreads();
    for (int i = tid; i < D_STATE * D_MODEL; i += 256) {
        int s = i >> 9, m = i & 511;
        wb[s][m] = W_B[i] * bbars[s];
    }
    __syncthreads();

    const int s    = lane & 15;
    const int q    = lane >> 4;
    const int rloc = q + (wave << 2);
    const int row  = blockIdx.x * 16 + rloc;
    const float* xr = x + (size_t)row * D_MODEL;

    float acc = 0.f;
    #pragma unroll 4
    for (int m = 0; m < D_MODEL; m += 4) {
        float4 xv = *(const float4*)(xr + m);
        float4 wv = *(const float4*)(&wb[s][m]);
        acc += xv.x * wv.x + xv.y * wv.y + xv.z * wv.z + xv.w * wv.w;
    }

    float abar = abars[s];
    float a = abar, b = acc;
    {
        float ap = __shfl_up(a, 16), bp = __shfl_up(b, 16);
        if (lane >= 16) { b = a * bp + b; a = a * ap; }
    }
    {
        float ap = __shfl_up(a, 32), bp = __shfl_up(b, 32);
        if (lane >= 32) { b = a * bp + b; a = a * ap; }
    }
    if (q == 3) w4[wave][s] = b;
    __syncthreads();
    float a4 = abar * abar; a4 = a4 * a4;
    float pb = 0.f;
    for (int w = 0; w < wave; ++w) pb = a4 * pb + w4[w][s];
    float hloc = a * pb + b;

    hL[(size_t)row * D_STATE + s] = hloc;
    if (rloc == 15) states[(size_t)blockIdx.x * D_STATE + s] = hloc;
}

// ---------------------------------------------------------------------------
// kc (512 blocks x 256): R7 convoy skeleton, BK=64 (8 K-steps), A fully
// preloaded in registers, single 64KB Bsub panel, f32 h@W_C^T epilogue.
// ---------------------------------------------------------------------------
#define CBM 16
#define BKC 64
__global__ __launch_bounds__(256) void kc_fused(
    const float*  __restrict__ x,      // (8192,512)
    const ushort* __restrict__ Wg,     // bf16 (512,512)
    const float*  __restrict__ hL,     // (8192,16)
    const float*  __restrict__ states, // (512,16)
    const float*  __restrict__ A_log,
    const float*  __restrict__ W_C,    // (512,16)
    const float*  __restrict__ Dvec,
    const float*  __restrict__ bg,
    const float*  __restrict__ gamma,
    const float*  __restrict__ beta,
    float* __restrict__ out) {
    __shared__ ushort Bsub[512 * BKC];      // 64 KB (aliased as f32 stg in prologue)
    __shared__ float  hsf[CBM][D_STATE];    // 1 KB
    __shared__ float  red[4][CBM][2];       // 512 B

    const int tid  = threadIdx.x;
    const int lane = tid & 63, wave = tid >> 6;
    const int r0   = blockIdx.x * CBM;
    const int fr   = lane & 15, kg = lane >> 4;
    const int colw = wave * 128;

    // ---- A preload: whole 16x512 A-slab as bf16 in regs (64 VGPR) ----
    short8 afp[8][2];
    #pragma unroll
    for (int t = 0; t < 8; ++t) {
        const float* ap = x + (size_t)(r0 + fr) * D_MODEL + t * 64 + kg * 8;
        float4 u0 = *(const float4*)ap;
        float4 u1 = *(const float4*)(ap + 4);
        float4 v0 = *(const float4*)(ap + 32);
        float4 v1 = *(const float4*)(ap + 36);
        float uu[8] = {u0.x,u0.y,u0.z,u0.w,u1.x,u1.y,u1.z,u1.w};
        float vv[8] = {v0.x,v0.y,v0.z,v0.w,v1.x,v1.y,v1.z,v1.w};
        #pragma unroll
        for (int e = 0; e < 8; ++e) {
            afp[t][0][e] = (short)f2bf(uu[e]);
            afp[t][1][e] = (short)f2bf(vv[e]);
        }
    }

    // ---- chunk-prefix combine -> hsf (f32); stg aliases Bsub ----
    float* stg = (float*)Bsub;
    const int c0 = blockIdx.x & 127;
    for (int i = tid; i < c0 * 16; i += 256)
        stg[i] = states[(size_t)(blockIdx.x - c0) * 16 + i];
    __syncthreads();
    {
        int s = tid & 15, nloc = tid >> 4;
        float A   = -fminf(fmaxf(expf(A_log[s]), EPSF), 10.0f);
        float a16 = expf(A * DT * 16.0f);
        float p = 0.f;
        for (int cc = 0; cc < c0; ++cc) p = a16 * p + stg[cc * 16 + s];
        float hv = expf(A * DT * (float)(nloc + 1)) * p
                 + hL[(size_t)(r0 + nloc) * D_STATE + s];
        hsf[nloc][s] = fminf(fmaxf(hv, -10.f), 10.f);
    }

    // ---- gate GEMM: 8 K-steps of BK=64, single-buffer convoy ----
    floatx4 acc[8] = {};
    #pragma unroll
    for (int t = 0; t < 8; ++t) {
        __syncthreads();          // Bsub free (prev frag reads / prologue stg reads done)
        #pragma unroll
        for (int is = 0; is < 16; ++is) {     // 64 KB panel: 512 rows x 64 k
            int row_ = is * 32 + (tid >> 3);
            int g_   = (tid & 7) ^ (row_ & 7);
            const ushort* gsrc_ = Wg + (size_t)row_ * D_MODEL + t * 64 + g_ * 8;
            __builtin_amdgcn_global_load_lds(
                (const __attribute__((address_space(1))) void*)gsrc_,
                (__attribute__((address_space(3))) void*)((char*)Bsub + is * 4096 + tid * 16),
                16, 0, 0);
        }
        __syncthreads();          // full drain: panel ready

        #pragma unroll
        for (int j = 0; j < 8; ++j) {
            int rb = colw + j * 16 + fr;
            short8 b0 = *(const short8*)(Bsub + (size_t)rb * BKC + (((kg    ) ^ (rb & 7)) * 8));
            short8 b1 = *(const short8*)(Bsub + (size_t)rb * BKC + (((kg + 4) ^ (rb & 7)) * 8));
            acc[j] = __builtin_amdgcn_mfma_f32_16x16x32_bf16(afp[t][0], b0, acc[j], 0, 0, 0);
            acc[j] = __builtin_amdgcn_mfma_f32_16x16x32_bf16(afp[t][1], b1, acc[j], 0, 0, 0);
        }
    }

    // ---- epilogue: y = h@W_C^T (f32 VALU) + D*x, blend, LayerNorm ----
    float vsum[4] = {}, vsq[4] = {};
    #pragma unroll
    for (int j = 0; j < 8; ++j) {
        int col = colw + j * 16 + fr;
        float dv = Dvec[col], bgv = bg[col];
        const float4* wcp = (const float4*)(W_C + (size_t)col * D_STATE);
        float4 w0 = wcp[0], w1 = wcp[1], w2 = wcp[2], w3 = wcp[3];
        #pragma unroll
        for (int q = 0; q < 4; ++q) {
            int rl = kg * 4 + q;
            float xv = x[(size_t)(r0 + rl) * D_MODEL + col];
            const float* hp = hsf[rl];
            float yv = dv * xv
                + hp[0]*w0.x + hp[1]*w0.y + hp[2]*w0.z + hp[3]*w0.w
                + hp[4]*w1.x + hp[5]*w1.y + hp[6]*w1.z + hp[7]*w1.w
                + hp[8]*w2.x + hp[9]*w2.y + hp[10]*w2.z + hp[11]*w2.w
                + hp[12]*w3.x + hp[13]*w3.y + hp[14]*w3.z + hp[15]*w3.w;
            float lg = acc[j][q] + bgv;
            float gt = 1.f / (1.f + expf(-lg));
            float v  = gt * yv + (1.f - gt) * xv;
            acc[j][q] = v;
            vsum[q] += v;
            vsq[q]  += v * v;
        }
    }
    #pragma unroll
    for (int off = 1; off < 16; off <<= 1) {
        #pragma unroll
        for (int q = 0; q < 4; ++q) {
            vsum[q] += __shfl_xor(vsum[q], off);
            vsq[q]  += __shfl_xor(vsq[q], off);
        }
    }
    if (fr == 0) {
        #pragma unroll
        for (int q = 0; q < 4; ++q) {
            red[wave][kg * 4 + q][0] = vsum[q];
            red[wave][kg * 4 + q][1] = vsq[q];
        }
    }
    __syncthreads();
    float mu[4], rs[4];
    #pragma unroll
    for (int q = 0; q < 4; ++q) {
        int rl = kg * 4 + q;
        float s = 0.f, ss = 0.f;
        #pragma unroll
        for (int w = 0; w < 4; ++w) { s += red[w][rl][0]; ss += red[w][rl][1]; }
        float m   = s * (1.f / (float)D_MODEL);
        float var = ss * (1.f / (float)D_MODEL) - m * m;
        mu[q] = m;
        rs[q] = rsqrtf(var + LN_EPSF);
    }
    #pragma unroll
    for (int j = 0; j < 8; ++j) {
        int col = colw + j * 16 + fr;
        float ga = gamma[col], be = beta[col];
        #pragma unroll
        for (int q = 0; q < 4; ++q)
            out[(size_t)(r0 + kg * 4 + q) * D_MODEL + col] =
                (acc[j][q] - mu[q]) * rs[q] * ga + be;
    }
}

// ---------------------------------------------------------------------------
extern "C" void kernel_launch(void* const* d_in, const int* in_sizes, int n_in,
                              void* d_out, int out_size, void* d_ws, size_t ws_size,
                              hipStream_t stream) {
    const float* x     = (const float*)d_in[0];
    const float* A_log = (const float*)d_in[1];
    const float* W_B   = (const float*)d_in[2];
    const float* W_C   = (const float*)d_in[3];
    const float* Dv    = (const float*)d_in[4];
    const float* Wg    = (const float*)d_in[5];
    const float* bg    = (const float*)d_in[6];
    const float* gamma = (const float*)d_in[7];
    const float* beta  = (const float*)d_in[8];
    float* out = (float*)d_out;

    const int rows = NBATCH * NSEQ;                            // 8192

    ushort* wgb    = (ushort*)d_ws;                            // 512 KB
    float*  hL     = (float*)(wgb + (size_t)D_MODEL * D_MODEL);// 512 KB
    float*  states = hL + (size_t)rows * D_STATE;              // 32 KB

    hipLaunchKernelGGL(kP, dim3(rows / 16), dim3(256), 0, stream,
                       x, A_log, W_B, Wg, wgb, hL, states);
    hipLaunchKernelGGL(kc_fused, dim3(rows / CBM), dim3(256), 0, stream,
                       x, wgb, hL, states, A_log, W_C, Dv, bg, gamma, beta, out);
}

// Round 14
// 50.402 us; speedup vs baseline: 1.3704x; 1.1617x over previous
//
#include <hip/hip_runtime.h>
#include <math.h>
#include <stdint.h>

#define D_MODEL 512
#define D_STATE 16
#define NSEQ    2048
#define NBATCH  4
#define EPSF    1e-8f
#define LN_EPSF 1e-5f
#define DT      (1.0f / 2048.0f)

typedef __attribute__((ext_vector_type(8))) short short8;
typedef __attribute__((ext_vector_type(4))) float floatx4;

__device__ __forceinline__ ushort f2bf(float f) {
    uint32_t u = __float_as_uint(f);
    return (ushort)((u + 0x7fffu + ((u >> 16) & 1u)) >> 16);
}

// ---------------------------------------------------------------------------
// kP (512 blocks x 256): per block = 16 rows (= one scan chunk).
// Byte-identical to the validated R7/R12 version.
// ---------------------------------------------------------------------------
__global__ __launch_bounds__(256) void kP(const float* __restrict__ x,
                                          const float* __restrict__ A_log,
                                          const float* __restrict__ W_B,
                                          const float* __restrict__ Wg,
                                          ushort* __restrict__ wgb,
                                          float* __restrict__ hL,
                                          float* __restrict__ states) {
    __shared__ float wb[D_STATE][D_MODEL + 4];
    __shared__ float bbars[16], abars[16];
    __shared__ float w4[4][16];
    const int tid = threadIdx.x, lane = tid & 63, wave = tid >> 6;

    if (tid < 64) {                       // W_gate cvt slice
        int i = blockIdx.x * 64 + tid;
        const float4* sp = (const float4*)Wg + (size_t)i * 2;
        float4 a = sp[0], b = sp[1];
        float v[8] = {a.x, a.y, a.z, a.w, b.x, b.y, b.z, b.w};
        short8 o;
        #pragma unroll
        for (int j = 0; j < 8; ++j) o[j] = (short)f2bf(v[j]);
        *(short8*)(wgb + (size_t)i * 8) = o;
    }
    if (tid < 16) {
        float A    = -fminf(fmaxf(expf(A_log[tid]), EPSF), 10.0f);
        float Abar = expf(A * DT);
        abars[tid] = Abar;
        bbars[tid] = (fabsf(A) > EPSF) ? (Abar - 1.0f) / (A + EPSF) : DT;
    }
    __syncthreads();
    for (int i = tid; i < D_STATE * D_MODEL; i += 256) {
        int s = i >> 9, m = i & 511;
        wb[s][m] = W_B[i] * bbars[s];
    }
    __syncthreads();

    const int s    = lane & 15;
    const int q    = lane >> 4;
    const int rloc = q + (wave << 2);
    const int row  = blockIdx.x * 16 + rloc;
    const float* xr = x + (size_t)row * D_MODEL;

    float acc = 0.f;
    #pragma unroll 4
    for (int m = 0; m < D_MODEL; m += 4) {
        float4 xv = *(const float4*)(xr + m);
        float4 wv = *(const float4*)(&wb[s][m]);
        acc += xv.x * wv.x + xv.y * wv.y + xv.z * wv.z + xv.w * wv.w;
    }

    float abar = abars[s];
    float a = abar, b = acc;
    {
        float ap = __shfl_up(a, 16), bp = __shfl_up(b, 16);
        if (lane >= 16) { b = a * bp + b; a = a * ap; }
    }
    {
        float ap = __shfl_up(a, 32), bp = __shfl_up(b, 32);
        if (lane >= 32) { b = a * bp + b; a = a * ap; }
    }
    if (q == 3) w4[wave][s] = b;
    __syncthreads();
    float a4 = abar * abar; a4 = a4 * a4;
    float pb = 0.f;
    for (int w = 0; w < wave; ++w) pb = a4 * pb + w4[w][s];
    float hloc = a * pb + b;

    hL[(size_t)row * D_STATE + s] = hloc;
    if (rloc == 15) states[(size_t)blockIdx.x * D_STATE + s] = hloc;
}

// ---------------------------------------------------------------------------
// kc (256 blocks x 512 thr = 8 waves, 1 block/CU): CBM=32, BK=64 (8 steps),
// single-buffer convoy (R12-validated skeleton). Wave w = rows
// (w>>2)*16..+15, cols (w&3)*128..+127 -- per-wave code identical to R12.
// Wg staged ONCE per block (512KB/CU, half of R12). f32 h@W_C^T epilogue.
// ---------------------------------------------------------------------------
#define CBM 32
#define BKC 64
__global__ __launch_bounds__(512) void kc_fused(
    const float*  __restrict__ x,      // (8192,512)
    const ushort* __restrict__ Wg,     // bf16 (512,512)
    const float*  __restrict__ hL,     // (8192,16)
    const float*  __restrict__ states, // (512,16)
    const float*  __restrict__ A_log,
    const float*  __restrict__ W_C,    // (512,16)
    const float*  __restrict__ Dvec,
    const float*  __restrict__ bg,
    const float*  __restrict__ gamma,
    const float*  __restrict__ beta,
    float* __restrict__ out) {
    __shared__ ushort Bsub[512 * BKC];      // 64 KB (aliased as f32 stg in prologue)
    __shared__ float  hsf[CBM][D_STATE];    // 2 KB
    __shared__ float  red[8][CBM][2];       // 2 KB

    const int tid  = threadIdx.x;             // 0..511
    const int lane = tid & 63, wave = tid >> 6;
    const int r0   = blockIdx.x * CBM;
    const int fr   = lane & 15, kg = lane >> 4;
    const int rbase = r0 + (wave >> 2) * 16;  // wave's 16-row slab
    const int colw  = (wave & 3) * 128;       // wave's 128-col stripe

    // ---- A preload: wave's 16x512 A-slab as bf16 in regs (64 VGPR) ----
    short8 afp[8][2];
    #pragma unroll
    for (int t = 0; t < 8; ++t) {
        const float* ap = x + (size_t)(rbase + fr) * D_MODEL + t * 64 + kg * 8;
        float4 u0 = *(const float4*)ap;
        float4 u1 = *(const float4*)(ap + 4);
        float4 v0 = *(const float4*)(ap + 32);
        float4 v1 = *(const float4*)(ap + 36);
        float uu[8] = {u0.x,u0.y,u0.z,u0.w,u1.x,u1.y,u1.z,u1.w};
        float vv[8] = {v0.x,v0.y,v0.z,v0.w,v1.x,v1.y,v1.z,v1.w};
        #pragma unroll
        for (int e = 0; e < 8; ++e) {
            afp[t][0][e] = (short)f2bf(uu[e]);
            afp[t][1][e] = (short)f2bf(vv[e]);
        }
    }

    // ---- chunk-prefix combine -> hsf (f32); stg aliases Bsub ----
    // Block covers chunks 2*bid, 2*bid+1. c0 = chunks before, within batch.
    float* stg = (float*)Bsub;
    const int c0    = (blockIdx.x & 63) * 2;
    const int cbase = (blockIdx.x >> 6) * 128;     // batch's first chunk
    for (int i = tid; i < (c0 + 1) * 16; i += 512)
        stg[i] = states[(size_t)cbase * 16 + i];
    __syncthreads();
    {
        int s = tid & 15, nloc = tid >> 4;          // nloc 0..31
        float A   = -fminf(fmaxf(expf(A_log[s]), EPSF), 10.0f);
        float a16 = expf(A * DT * 16.0f);
        int nch = c0 + (nloc >> 4);                 // chunks in this row's prefix
        float p = 0.f;
        for (int cc = 0; cc < nch; ++cc) p = a16 * p + stg[cc * 16 + s];
        float hv = expf(A * DT * (float)((nloc & 15) + 1)) * p
                 + hL[(size_t)(r0 + nloc) * D_STATE + s];
        hsf[nloc][s] = fminf(fmaxf(hv, -10.f), 10.f);
    }

    // ---- gate GEMM: 8 K-steps of BK=64, single-buffer convoy ----
    floatx4 acc[8] = {};
    #pragma unroll
    for (int t = 0; t < 8; ++t) {
        __syncthreads();          // Bsub free (prev frag reads / prologue stg reads done)
        #pragma unroll
        for (int is = 0; is < 8; ++is) {      // 64 KB panel: 512 rows x 64 k
            int row_ = is * 64 + (tid >> 3);
            int g_   = (tid & 7) ^ (row_ & 7);
            const ushort* gsrc_ = Wg + (size_t)row_ * D_MODEL + t * 64 + g_ * 8;
            __builtin_amdgcn_global_load_lds(
                (const __attribute__((address_space(1))) void*)gsrc_,
                (__attribute__((address_space(3))) void*)((char*)Bsub + is * 8192 + tid * 16),
                16, 0, 0);
        }
        __syncthreads();          // full drain: panel ready

        #pragma unroll
        for (int j = 0; j < 8; ++j) {
            int rb = colw + j * 16 + fr;
            short8 b0 = *(const short8*)(Bsub + (size_t)rb * BKC + (((kg    ) ^ (rb & 7)) * 8));
            short8 b1 = *(const short8*)(Bsub + (size_t)rb * BKC + (((kg + 4) ^ (rb & 7)) * 8));
            acc[j] = __builtin_amdgcn_mfma_f32_16x16x32_bf16(afp[t][0], b0, acc[j], 0, 0, 0);
            acc[j] = __builtin_amdgcn_mfma_f32_16x16x32_bf16(afp[t][1], b1, acc[j], 0, 0, 0);
        }
    }

    // ---- epilogue: y = h@W_C^T (f32 VALU) + D*x, blend, LayerNorm ----
    // Thread's rows: rloc = (wave>>2)*16 + kg*4+q (local to block).
    float vsum[4] = {}, vsq[4] = {};
    #pragma unroll
    for (int j = 0; j < 8; ++j) {
        int col = colw + j * 16 + fr;
        float dv = Dvec[col], bgv = bg[col];
        const float4* wcp = (const float4*)(W_C + (size_t)col * D_STATE);
        float4 w0 = wcp[0], w1 = wcp[1], w2 = wcp[2], w3 = wcp[3];
        #pragma unroll
        for (int q = 0; q < 4; ++q) {
            int rloc = (wave >> 2) * 16 + kg * 4 + q;
            float xv = x[(size_t)(r0 + rloc) * D_MODEL + col];
            const float* hp = hsf[rloc];
            float yv = dv * xv
                + hp[0]*w0.x + hp[1]*w0.y + hp[2]*w0.z + hp[3]*w0.w
                + hp[4]*w1.x + hp[5]*w1.y + hp[6]*w1.z + hp[7]*w1.w
                + hp[8]*w2.x + hp[9]*w2.y + hp[10]*w2.z + hp[11]*w2.w
                + hp[12]*w3.x + hp[13]*w3.y + hp[14]*w3.z + hp[15]*w3.w;
            float lg = acc[j][q] + bgv;
            float gt = 1.f / (1.f + expf(-lg));
            float v  = gt * yv + (1.f - gt) * xv;
            acc[j][q] = v;
            vsum[q] += v;
            vsq[q]  += v * v;
        }
    }
    #pragma unroll
    for (int off = 1; off < 16; off <<= 1) {
        #pragma unroll
        for (int q = 0; q < 4; ++q) {
            vsum[q] += __shfl_xor(vsum[q], off);
            vsq[q]  += __shfl_xor(vsq[q], off);
        }
    }
    if (fr == 0) {
        #pragma unroll
        for (int q = 0; q < 4; ++q) {
            int rloc = (wave >> 2) * 16 + kg * 4 + q;
            red[wave][rloc][0] = vsum[q];
            red[wave][rloc][1] = vsq[q];
        }
    }
    __syncthreads();
    float mu[4], rs[4];
    #pragma unroll
    for (int q = 0; q < 4; ++q) {
        int rloc = (wave >> 2) * 16 + kg * 4 + q;
        int wg0  = (wave >> 2) * 4;                // the 4 waves sharing these rows
        float s = 0.f, ss = 0.f;
        #pragma unroll
        for (int w = 0; w < 4; ++w) {
            s  += red[wg0 + w][rloc][0];
            ss += red[wg0 + w][rloc][1];
        }
        float m   = s * (1.f / (float)D_MODEL);
        float var = ss * (1.f / (float)D_MODEL) - m * m;
        mu[q] = m;
        rs[q] = rsqrtf(var + LN_EPSF);
    }
    #pragma unroll
    for (int j = 0; j < 8; ++j) {
        int col = colw + j * 16 + fr;
        float ga = gamma[col], be = beta[col];
        #pragma unroll
        for (int q = 0; q < 4; ++q) {
            int rloc = (wave >> 2) * 16 + kg * 4 + q;
            out[(size_t)(r0 + rloc) * D_MODEL + col] =
                (acc[j][q] - mu[q]) * rs[q] * ga + be;
        }
    }
}

// ---------------------------------------------------------------------------
extern "C" void kernel_launch(void* const* d_in, const int* in_sizes, int n_in,
                              void* d_out, int out_size, void* d_ws, size_t ws_size,
                              hipStream_t stream) {
    const float* x     = (const float*)d_in[0];
    const float* A_log = (const float*)d_in[1];
    const float* W_B   = (const float*)d_in[2];
    const float* W_C   = (const float*)d_in[3];
    const float* Dv    = (const float*)d_in[4];
    const float* Wg    = (const float*)d_in[5];
    const float* bg    = (const float*)d_in[6];
    const float* gamma = (const float*)d_in[7];
    const float* beta  = (const float*)d_in[8];
    float* out = (float*)d_out;

    const int rows = NBATCH * NSEQ;                            // 8192

    ushort* wgb    = (ushort*)d_ws;                            // 512 KB
    float*  hL     = (float*)(wgb + (size_t)D_MODEL * D_MODEL);// 512 KB
    float*  states = hL + (size_t)rows * D_STATE;              // 32 KB

    hipLaunchKernelGGL(kP, dim3(rows / 16), dim3(256), 0, stream,
                       x, A_log, W_B, Wg, wgb, hL, states);
    hipLaunchKernelGGL(kc_fused, dim3(rows / CBM), dim3(512), 0, stream,
                       x, wgb, hL, states, A_log, W_C, Dv, bg, gamma, beta, out);
}